// Round 1
// baseline (614.427 us; speedup 1.0000x reference)
//
#include <hip/hip_runtime.h>
#include <math.h>

#define NN 20000
#define EE 320000
#define ET (EE + NN)
#define HC 256
#define EPS_BN 1e-5f

__device__ __forceinline__ float4 ld4(const float* p) { return *reinterpret_cast<const float4*>(p); }
__device__ __forceinline__ void st4(float* p, float4 v) { *reinterpret_cast<float4*>(p) = v; }
__device__ __forceinline__ float lrelu(float x) { return fmaxf(x, 0.f) + 0.2f * fminf(x, 0.f); }

// ---------------- GEMM: C[M,256] = A[M,K] @ B[K,256], row-major ----------------
__global__ __launch_bounds__(256) void gemm64(const float* __restrict__ A,
                                              const float* __restrict__ B,
                                              float* __restrict__ C,
                                              int M, int K) {
  __shared__ float As[16][65];   // [k][m], +1 pad
  __shared__ float Bs[16][64];   // [k][n]
  const int tid = threadIdx.x;
  const int tx = tid & 15, ty = tid >> 4;
  const int row0 = blockIdx.y * 64;
  const int col0 = blockIdx.x * 64;
  float acc[4][4] = {{0.f, 0.f, 0.f, 0.f}, {0.f, 0.f, 0.f, 0.f},
                     {0.f, 0.f, 0.f, 0.f}, {0.f, 0.f, 0.f, 0.f}};
  for (int kk = 0; kk < K; kk += 16) {
    // A tile: 64 rows x 16 k  (thread: row tid>>2, k quad (tid&3)*4)
    {
      int r = tid >> 2;
      int kq = (tid & 3) << 2;
      int grow = row0 + r;
      float4 av = make_float4(0.f, 0.f, 0.f, 0.f);
      if (grow < M) av = ld4(&A[(size_t)grow * K + kk + kq]);
      As[kq + 0][r] = av.x; As[kq + 1][r] = av.y;
      As[kq + 2][r] = av.z; As[kq + 3][r] = av.w;
    }
    // B tile: 16 k x 64 cols
    {
      int br = tid >> 4;
      int bc = (tid & 15) << 2;
      float4 bv = ld4(&B[(size_t)(kk + br) * HC + col0 + bc]);
      *reinterpret_cast<float4*>(&Bs[br][bc]) = bv;
    }
    __syncthreads();
#pragma unroll
    for (int k = 0; k < 16; ++k) {
      float a0 = As[k][ty * 4 + 0], a1 = As[k][ty * 4 + 1];
      float a2 = As[k][ty * 4 + 2], a3 = As[k][ty * 4 + 3];
      float b0 = Bs[k][tx * 4 + 0], b1 = Bs[k][tx * 4 + 1];
      float b2 = Bs[k][tx * 4 + 2], b3 = Bs[k][tx * 4 + 3];
      acc[0][0] += a0 * b0; acc[0][1] += a0 * b1; acc[0][2] += a0 * b2; acc[0][3] += a0 * b3;
      acc[1][0] += a1 * b0; acc[1][1] += a1 * b1; acc[1][2] += a1 * b2; acc[1][3] += a1 * b3;
      acc[2][0] += a2 * b0; acc[2][1] += a2 * b1; acc[2][2] += a2 * b2; acc[2][3] += a2 * b3;
      acc[3][0] += a3 * b0; acc[3][1] += a3 * b1; acc[3][2] += a3 * b2; acc[3][3] += a3 * b3;
    }
    __syncthreads();
  }
#pragma unroll
  for (int i = 0; i < 4; ++i) {
    int gr = row0 + ty * 4 + i;
    if (gr < M) {
      float4 v = make_float4(acc[i][0], acc[i][1], acc[i][2], acc[i][3]);
      st4(&C[(size_t)gr * HC + col0 + tx * 4], v);
    }
  }
}

// ---------------- CSR build (counting sort by dst) ----------------
__global__ __launch_bounds__(256) void hist_kernel(const int* __restrict__ ei,
                                                   int* __restrict__ counts) {
  int e = blockIdx.x * blockDim.x + threadIdx.x;
  if (e >= ET) return;
  int d = (e < EE) ? ei[EE + e] : (e - EE);
  atomicAdd(&counts[d], 1);
}

__global__ __launch_bounds__(1024) void scan_kernel(int* __restrict__ cursor,  // in: counts, out: start offsets
                                                    int* __restrict__ offsets) {
  __shared__ int sdata[1024];
  __shared__ int carry;
  const int tid = threadIdx.x;
  if (tid == 0) carry = 0;
  __syncthreads();
  for (int base = 0; base < NN; base += 1024) {
    int i = base + tid;
    int v = (i < NN) ? cursor[i] : 0;
    sdata[tid] = v;
    __syncthreads();
    for (int off = 1; off < 1024; off <<= 1) {
      int t = (tid >= off) ? sdata[tid - off] : 0;
      __syncthreads();
      sdata[tid] += t;
      __syncthreads();
    }
    int excl = sdata[tid] - v + carry;
    if (i < NN) { offsets[i] = excl; cursor[i] = excl; }
    __syncthreads();
    if (tid == 0) carry += sdata[1023];
    __syncthreads();
  }
  if (tid == 0) offsets[NN] = carry;
}

__global__ __launch_bounds__(256) void scatter_kernel(const int* __restrict__ ei,
                                                      int* __restrict__ cursor,
                                                      int* __restrict__ srcs) {
  int e = blockIdx.x * blockDim.x + threadIdx.x;
  if (e >= ET) return;
  int s, d;
  if (e < EE) { s = ei[e]; d = ei[EE + e]; } else { s = d = e - EE; }
  int pos = atomicAdd(&cursor[d], 1);
  srcs[pos] = s;
}

// ---------------- GATv2 layer: one wave per node, online softmax + BN + ELU ----------------
__global__ __launch_bounds__(256) void gat_layer(const float* __restrict__ xl,
                                                 const float* __restrict__ xr,
                                                 const float* __restrict__ att,
                                                 const float* __restrict__ bias,
                                                 const float* __restrict__ gam,
                                                 const float* __restrict__ bet,
                                                 const float* __restrict__ mean,
                                                 const float* __restrict__ var,
                                                 const int* __restrict__ offsets,
                                                 const int* __restrict__ srcs,
                                                 float* __restrict__ out) {
  const int wave = threadIdx.x >> 6;
  const int lane = threadIdx.x & 63;
  const int node = blockIdx.x * 4 + wave;
  if (node >= NN) return;

  const float4 xr4 = ld4(&xr[(size_t)node * HC + lane * 4]);
  const float4 a4 = ld4(&att[lane * 4]);
  const int beg = offsets[node];
  const int end = offsets[node + 1];

  float m_run = -1e30f, l_run = 0.f;
  float4 O = make_float4(0.f, 0.f, 0.f, 0.f);

  for (int i = beg; i < end; ++i) {
    int s = srcs[i];
    float4 xl4 = ld4(&xl[(size_t)s * HC + lane * 4]);
    float mx = xl4.x + xr4.x, my = xl4.y + xr4.y;
    float mz = xl4.z + xr4.z, mw = xl4.w + xr4.w;
    float loc = lrelu(mx) * a4.x + lrelu(my) * a4.y + lrelu(mz) * a4.z + lrelu(mw) * a4.w;
    loc += __shfl_xor(loc, 1);
    loc += __shfl_xor(loc, 2);
    loc += __shfl_xor(loc, 4);
    loc += __shfl_xor(loc, 8);   // now all 16 lanes of this head hold e_h
    float mn = fmaxf(m_run, loc);
    float sc = __expf(m_run - mn);
    float p = __expf(loc - mn);
    l_run = l_run * sc + p;
    O.x = O.x * sc + p * xl4.x;
    O.y = O.y * sc + p * xl4.y;
    O.z = O.z * sc + p * xl4.z;
    O.w = O.w * sc + p * xl4.w;
    m_run = mn;
  }
  float inv = 1.f / l_run;

  // epilogue: + bias, BN(eval), ELU
  float4 b4 = ld4(&bias[lane * 4]);
  float4 g4 = ld4(&gam[lane * 4]);
  float4 e4 = ld4(&bet[lane * 4]);
  float4 m4 = ld4(&mean[lane * 4]);
  float4 v4 = ld4(&var[lane * 4]);
  float y[4] = {O.x * inv + b4.x, O.y * inv + b4.y, O.z * inv + b4.z, O.w * inv + b4.w};
  float gg[4] = {g4.x, g4.y, g4.z, g4.w};
  float bb[4] = {e4.x, e4.y, e4.z, e4.w};
  float mm[4] = {m4.x, m4.y, m4.z, m4.w};
  float vv[4] = {v4.x, v4.y, v4.z, v4.w};
  float r[4];
#pragma unroll
  for (int j = 0; j < 4; ++j) {
    float sc = gg[j] * rsqrtf(vv[j] + EPS_BN);
    float z = (y[j] - mm[j]) * sc + bb[j];
    r[j] = (z > 0.f) ? z : expm1f(z);
  }
  st4(&out[(size_t)node * HC + lane * 4], make_float4(r[0], r[1], r[2], r[3]));
}

// ---------------- layer 2: 256 -> 2 projections (wave per node) ----------------
__global__ __launch_bounds__(256) void lin2_kernel(const float* __restrict__ h,
                                                   const float* __restrict__ Wl,
                                                   const float* __restrict__ Wr,
                                                   float* __restrict__ xl2,
                                                   float* __restrict__ xr2) {
  const int wave = threadIdx.x >> 6;
  const int lane = threadIdx.x & 63;
  const int node = blockIdx.x * 4 + wave;
  if (node >= NN) return;
  float4 h4 = ld4(&h[(size_t)node * HC + lane * 4]);
  float hv[4] = {h4.x, h4.y, h4.z, h4.w};
  float l0 = 0.f, l1 = 0.f, r0 = 0.f, r1 = 0.f;
#pragma unroll
  for (int j = 0; j < 4; ++j) {
    int row = lane * 4 + j;
    l0 += hv[j] * Wl[row * 2 + 0];
    l1 += hv[j] * Wl[row * 2 + 1];
    r0 += hv[j] * Wr[row * 2 + 0];
    r1 += hv[j] * Wr[row * 2 + 1];
  }
#pragma unroll
  for (int off = 1; off < 64; off <<= 1) {
    l0 += __shfl_xor(l0, off);
    l1 += __shfl_xor(l1, off);
    r0 += __shfl_xor(r0, off);
    r1 += __shfl_xor(r1, off);
  }
  if (lane == 0) {
    xl2[node * 2 + 0] = l0; xl2[node * 2 + 1] = l1;
    xr2[node * 2 + 0] = r0; xr2[node * 2 + 1] = r1;
  }
}

// ---------------- layer 2 attention + log_softmax (thread per node) ----------------
__global__ __launch_bounds__(256) void gat2_out_kernel(const float* __restrict__ xl2,
                                                       const float* __restrict__ xr2,
                                                       const float* __restrict__ att2,
                                                       const float* __restrict__ b2,
                                                       const int* __restrict__ offsets,
                                                       const int* __restrict__ srcs,
                                                       float* __restrict__ out) {
  int node = blockIdx.x * blockDim.x + threadIdx.x;
  if (node >= NN) return;
  float a0 = att2[0], a1 = att2[1];
  float xr0 = xr2[node * 2 + 0], xr1 = xr2[node * 2 + 1];
  int beg = offsets[node], end = offsets[node + 1];
  float m_run = -1e30f, l_run = 0.f, o0 = 0.f, o1 = 0.f;
  for (int i = beg; i < end; ++i) {
    int s = srcs[i];
    float x0 = xl2[s * 2 + 0], x1 = xl2[s * 2 + 1];
    float e = lrelu(x0 + xr0) * a0 + lrelu(x1 + xr1) * a1;
    float mn = fmaxf(m_run, e);
    float sc = __expf(m_run - mn);
    float p = __expf(e - mn);
    l_run = l_run * sc + p;
    o0 = o0 * sc + p * x0;
    o1 = o1 * sc + p * x1;
    m_run = mn;
  }
  float inv = 1.f / l_run;
  float t0 = o0 * inv + b2[0];
  float t1 = o1 * inv + b2[1];
  float mx = fmaxf(t0, t1);
  float ls = mx + logf(__expf(t0 - mx) + __expf(t1 - mx));
  out[node * 2 + 0] = t0 - ls;
  out[node * 2 + 1] = t1 - ls;
}

extern "C" void kernel_launch(void* const* d_in, const int* in_sizes, int n_in,
                              void* d_out, int out_size, void* d_ws, size_t ws_size,
                              hipStream_t stream) {
  const float* x    = (const float*)d_in[0];
  const int*   ei   = (const int*)d_in[1];
  const float* Wl0  = (const float*)d_in[2];
  const float* Wr0  = (const float*)d_in[3];
  const float* att0 = (const float*)d_in[4];
  const float* b0   = (const float*)d_in[5];
  const float* g0   = (const float*)d_in[6];
  const float* be0  = (const float*)d_in[7];
  const float* m0   = (const float*)d_in[8];
  const float* v0   = (const float*)d_in[9];
  const float* Wl1  = (const float*)d_in[10];
  const float* Wr1  = (const float*)d_in[11];
  const float* att1 = (const float*)d_in[12];
  const float* b1   = (const float*)d_in[13];
  const float* g1   = (const float*)d_in[14];
  const float* be1  = (const float*)d_in[15];
  const float* m1   = (const float*)d_in[16];
  const float* v1   = (const float*)d_in[17];
  const float* Wl2  = (const float*)d_in[18];
  const float* Wr2  = (const float*)d_in[19];
  const float* att2 = (const float*)d_in[20];
  const float* b2   = (const float*)d_in[21];

  float* fws = (float*)d_ws;
  float* xl  = fws;                          // NN*HC
  float* xr  = xl + (size_t)NN * HC;         // NN*HC
  float* hA  = xr + (size_t)NN * HC;         // NN*HC
  float* xl2 = hA + (size_t)NN * HC;         // 2*NN
  float* xr2 = xl2 + 2 * NN;                 // 2*NN
  int* offsets = (int*)(xr2 + 2 * NN);       // NN+1
  int* cursor  = offsets + (NN + 1);         // NN
  int* srcs    = cursor + NN;                // ET

  // --- CSR build ---
  hipMemsetAsync(cursor, 0, NN * sizeof(int), stream);
  hist_kernel<<<(ET + 255) / 256, 256, 0, stream>>>(ei, cursor);
  scan_kernel<<<1, 1024, 0, stream>>>(cursor, offsets);
  scatter_kernel<<<(ET + 255) / 256, 256, 0, stream>>>(ei, cursor, srcs);

  dim3 gg(4, (NN + 63) / 64);
  // --- layer 0 ---
  gemm64<<<gg, 256, 0, stream>>>(x, Wl0, xl, NN, 512);
  gemm64<<<gg, 256, 0, stream>>>(x, Wr0, xr, NN, 512);
  gat_layer<<<NN / 4, 256, 0, stream>>>(xl, xr, att0, b0, g0, be0, m0, v0, offsets, srcs, hA);
  // --- layer 1 ---
  gemm64<<<gg, 256, 0, stream>>>(hA, Wl1, xl, NN, 256);
  gemm64<<<gg, 256, 0, stream>>>(hA, Wr1, xr, NN, 256);
  gat_layer<<<NN / 4, 256, 0, stream>>>(xl, xr, att1, b1, g1, be1, m1, v1, offsets, srcs, hA);
  // --- layer 2 ---
  lin2_kernel<<<NN / 4, 256, 0, stream>>>(hA, Wl2, Wr2, xl2, xr2);
  gat2_out_kernel<<<(NN + 255) / 256, 256, 0, stream>>>(xl2, xr2, att2, b2, offsets, srcs, (float*)d_out);
}

// Round 2
// 385.089 us; speedup vs baseline: 1.5955x; 1.5955x over previous
//
#include <hip/hip_runtime.h>
#include <math.h>

#define NN 20000
#define MP 20096          // NN padded to multiple of 128 for MFMA GEMM A-reads
#define EE 320000
#define ET (EE + NN)
#define HC 256
#define EPS_BN 1e-5f

typedef __bf16 bf16x8 __attribute__((ext_vector_type(8)));
typedef float f32x4 __attribute__((ext_vector_type(4)));

__device__ __forceinline__ float4 ld4(const float* p) { return *reinterpret_cast<const float4*>(p); }
__device__ __forceinline__ void st4(float* p, float4 v) { *reinterpret_cast<float4*>(p) = v; }
__device__ __forceinline__ float lrelu(float x) { return fmaxf(x, 0.f) + 0.2f * fminf(x, 0.f); }

// fp32 -> bf16 (RNE), raw ushort storage (no header-struct dependence)
__device__ __forceinline__ unsigned short f2b(float f) {
  unsigned int u = __float_as_uint(f);
  u = (u + 0x7fffu + ((u >> 16) & 1u)) >> 16;
  return (unsigned short)u;
}
__device__ __forceinline__ float b2f(unsigned short u) {
  return __uint_as_float(((unsigned int)u) << 16);
}

// async global->LDS, 16B per lane; LDS dest = wave-uniform base + lane*16
__device__ __forceinline__ void gld_lds16(const void* g, void* l) {
  __builtin_amdgcn_global_load_lds(
      (const __attribute__((address_space(1))) unsigned int*)g,
      (__attribute__((address_space(3))) unsigned int*)(unsigned int)(unsigned long long)l,
      16, 0, 0);
}

// ---------------- conversions ----------------
__global__ __launch_bounds__(256) void convert_x_kernel(const float* __restrict__ x,
                                                        unsigned short* __restrict__ xb) {
  int i = (blockIdx.x * 256 + threadIdx.x) * 4;
  if (i >= NN * 512) return;
  float4 v = ld4(&x[i]);
  ushort4 o;
  o.x = f2b(v.x); o.y = f2b(v.y); o.z = f2b(v.z); o.w = f2b(v.w);
  *reinterpret_cast<ushort4*>(&xb[i]) = o;
}

// Wf[n][k] = (n<256 ? Wl[k][n] : Wr[k][n-256])  (B^T layout, bf16)
__global__ __launch_bounds__(256) void convert_w_kernel(const float* __restrict__ Wl,
                                                        const float* __restrict__ Wr,
                                                        unsigned short* __restrict__ Wf,
                                                        int K) {
  int idx = blockIdx.x * 256 + threadIdx.x;
  if (idx >= 512 * K) return;
  int n = idx / K, k = idx - n * K;
  float v = (n < 256) ? Wl[(size_t)k * 256 + n] : Wr[(size_t)k * 256 + (n - 256)];
  Wf[idx] = f2b(v);
}

// ---------------- bf16 MFMA GEMM: C[M,512] = A[Mp,K](bf16) @ Bt[512,K]^T(bf16) ----------------
// 128x128 tile, BK=32, 256 threads = 4 waves, each wave a 64x64 sub-tile.
__global__ __launch_bounds__(256) void gemm_mfma(const unsigned short* __restrict__ A,
                                                 const unsigned short* __restrict__ Bt,
                                                 float* __restrict__ C,
                                                 int M, int K) {
  __shared__ unsigned short As[128 * 32];  // [r][k], 8 KB
  __shared__ unsigned short Bs[128 * 32];  // [n][k], 8 KB
  const int wave = threadIdx.x >> 6;
  const int lane = threadIdx.x & 63;
  const int am = lane & 15;      // m / n within 16-tile
  const int aq = lane >> 4;      // quad
  const int wr = (wave >> 1) * 64;  // wave sub-tile row origin
  const int wc = (wave & 1) * 64;   // wave sub-tile col origin
  const int row0 = blockIdx.y * 128;
  const int col0 = blockIdx.x * 128;

  f32x4 acc[4][4] = {};

  for (int kk = 0; kk < K; kk += 32) {
    __syncthreads();  // previous compute done before LDS overwrite
#pragma unroll
    for (int c = 0; c < 2; ++c) {
      int seg = wave * 128 + c * 64 + lane;     // 0..511
      int r = seg >> 2, ks = (seg & 3) * 8;
      gld_lds16(A + (size_t)(row0 + r) * K + kk + ks, &As[(wave * 128 + c * 64) * 8]);
      gld_lds16(Bt + (size_t)(col0 + r) * K + kk + ks, &Bs[(wave * 128 + c * 64) * 8]);
    }
    __syncthreads();  // drains vmcnt; LDS tiles ready

    bf16x8 af[4], bfr[4];
#pragma unroll
    for (int i = 0; i < 4; ++i)
      af[i] = *reinterpret_cast<const bf16x8*>(&As[(wr + i * 16 + am) * 32 + aq * 8]);
#pragma unroll
    for (int j = 0; j < 4; ++j)
      bfr[j] = *reinterpret_cast<const bf16x8*>(&Bs[(wc + j * 16 + am) * 32 + aq * 8]);
#pragma unroll
    for (int i = 0; i < 4; ++i)
#pragma unroll
      for (int j = 0; j < 4; ++j)
        acc[i][j] = __builtin_amdgcn_mfma_f32_16x16x32_bf16(af[i], bfr[j], acc[i][j], 0, 0, 0);
  }

  // epilogue: D col = lane&15, row = (lane>>4)*4 + reg
#pragma unroll
  for (int i = 0; i < 4; ++i) {
#pragma unroll
    for (int j = 0; j < 4; ++j) {
#pragma unroll
      for (int rr = 0; rr < 4; ++rr) {
        int grow = row0 + wr + i * 16 + aq * 4 + rr;
        int gcol = col0 + wc + j * 16 + am;
        if (grow < M) C[(size_t)grow * 512 + gcol] = acc[i][j][rr];
      }
    }
  }
}

// ---------------- CSR build (counting sort by dst) ----------------
__global__ __launch_bounds__(256) void hist_kernel(const int* __restrict__ ei,
                                                   int* __restrict__ counts) {
  int e = blockIdx.x * blockDim.x + threadIdx.x;
  if (e >= ET) return;
  int d = (e < EE) ? ei[EE + e] : (e - EE);
  atomicAdd(&counts[d], 1);
}

__global__ __launch_bounds__(1024) void scan_kernel(int* __restrict__ cursor,
                                                    int* __restrict__ offsets) {
  __shared__ int sdata[1024];
  __shared__ int carry;
  const int tid = threadIdx.x;
  if (tid == 0) carry = 0;
  __syncthreads();
  for (int base = 0; base < NN; base += 1024) {
    int i = base + tid;
    int v = (i < NN) ? cursor[i] : 0;
    sdata[tid] = v;
    __syncthreads();
    for (int off = 1; off < 1024; off <<= 1) {
      int t = (tid >= off) ? sdata[tid - off] : 0;
      __syncthreads();
      sdata[tid] += t;
      __syncthreads();
    }
    int excl = sdata[tid] - v + carry;
    if (i < NN) { offsets[i] = excl; cursor[i] = excl; }
    __syncthreads();
    if (tid == 0) carry += sdata[1023];
    __syncthreads();
  }
  if (tid == 0) offsets[NN] = carry;
}

__global__ __launch_bounds__(256) void scatter_kernel(const int* __restrict__ ei,
                                                      int* __restrict__ cursor,
                                                      int* __restrict__ srcs) {
  int e = blockIdx.x * blockDim.x + threadIdx.x;
  if (e >= ET) return;
  int s, d;
  if (e < EE) { s = ei[e]; d = ei[EE + e]; } else { s = d = e - EE; }
  int pos = atomicAdd(&cursor[d], 1);
  srcs[pos] = s;
}

// ---------------- GATv2 layer: wave/node, online softmax, BN+ELU, bf16 out ----------------
// xlr: [NN,512] fp32, row = [xl(256) | xr(256)]
__global__ __launch_bounds__(256) void gat_layer(const float* __restrict__ xlr,
                                                 const float* __restrict__ att,
                                                 const float* __restrict__ bias,
                                                 const float* __restrict__ gam,
                                                 const float* __restrict__ bet,
                                                 const float* __restrict__ mean,
                                                 const float* __restrict__ var,
                                                 const int* __restrict__ offsets,
                                                 const int* __restrict__ srcs,
                                                 unsigned short* __restrict__ hb) {
  const int wave = threadIdx.x >> 6;
  const int lane = threadIdx.x & 63;
  const int node = blockIdx.x * 4 + wave;
  if (node >= NN) return;

  const float4 xr4 = ld4(&xlr[(size_t)node * 512 + 256 + lane * 4]);
  const float4 a4 = ld4(&att[lane * 4]);
  const int beg = offsets[node];
  const int end = offsets[node + 1];

  float m_run = -1e30f, l_run = 0.f;
  float4 O = make_float4(0.f, 0.f, 0.f, 0.f);

  for (int i = beg; i < end; ++i) {
    int s = srcs[i];
    float4 xl4 = ld4(&xlr[(size_t)s * 512 + lane * 4]);
    float mx = xl4.x + xr4.x, my = xl4.y + xr4.y;
    float mz = xl4.z + xr4.z, mw = xl4.w + xr4.w;
    float loc = lrelu(mx) * a4.x + lrelu(my) * a4.y + lrelu(mz) * a4.z + lrelu(mw) * a4.w;
    loc += __shfl_xor(loc, 1);
    loc += __shfl_xor(loc, 2);
    loc += __shfl_xor(loc, 4);
    loc += __shfl_xor(loc, 8);   // all 16 lanes of this head hold e_h
    float mn = fmaxf(m_run, loc);
    float sc = __expf(m_run - mn);
    float p = __expf(loc - mn);
    l_run = l_run * sc + p;
    O.x = O.x * sc + p * xl4.x;
    O.y = O.y * sc + p * xl4.y;
    O.z = O.z * sc + p * xl4.z;
    O.w = O.w * sc + p * xl4.w;
    m_run = mn;
  }
  float inv = 1.f / l_run;

  float4 b4 = ld4(&bias[lane * 4]);
  float4 g4 = ld4(&gam[lane * 4]);
  float4 e4 = ld4(&bet[lane * 4]);
  float4 m4 = ld4(&mean[lane * 4]);
  float4 v4 = ld4(&var[lane * 4]);
  float y[4] = {O.x * inv + b4.x, O.y * inv + b4.y, O.z * inv + b4.z, O.w * inv + b4.w};
  float gg[4] = {g4.x, g4.y, g4.z, g4.w};
  float bb[4] = {e4.x, e4.y, e4.z, e4.w};
  float mm[4] = {m4.x, m4.y, m4.z, m4.w};
  float vv[4] = {v4.x, v4.y, v4.z, v4.w};
  ushort4 r;
  float z0 = (y[0] - mm[0]) * (gg[0] * rsqrtf(vv[0] + EPS_BN)) + bb[0];
  float z1 = (y[1] - mm[1]) * (gg[1] * rsqrtf(vv[1] + EPS_BN)) + bb[1];
  float z2 = (y[2] - mm[2]) * (gg[2] * rsqrtf(vv[2] + EPS_BN)) + bb[2];
  float z3 = (y[3] - mm[3]) * (gg[3] * rsqrtf(vv[3] + EPS_BN)) + bb[3];
  r.x = f2b(z0 > 0.f ? z0 : expm1f(z0));
  r.y = f2b(z1 > 0.f ? z1 : expm1f(z1));
  r.z = f2b(z2 > 0.f ? z2 : expm1f(z2));
  r.w = f2b(z3 > 0.f ? z3 : expm1f(z3));
  *reinterpret_cast<ushort4*>(&hb[(size_t)node * HC + lane * 4]) = r;
}

// ---------------- layer 2: 256 -> 2 projections (wave per node, bf16 input) ----------------
__global__ __launch_bounds__(256) void lin2_kernel(const unsigned short* __restrict__ hb,
                                                   const float* __restrict__ Wl,
                                                   const float* __restrict__ Wr,
                                                   float* __restrict__ xl2,
                                                   float* __restrict__ xr2) {
  const int wave = threadIdx.x >> 6;
  const int lane = threadIdx.x & 63;
  const int node = blockIdx.x * 4 + wave;
  if (node >= NN) return;
  ushort4 h4 = *reinterpret_cast<const ushort4*>(&hb[(size_t)node * HC + lane * 4]);
  float hv[4] = {b2f(h4.x), b2f(h4.y), b2f(h4.z), b2f(h4.w)};
  float l0 = 0.f, l1 = 0.f, r0 = 0.f, r1 = 0.f;
#pragma unroll
  for (int j = 0; j < 4; ++j) {
    int row = lane * 4 + j;
    l0 += hv[j] * Wl[row * 2 + 0];
    l1 += hv[j] * Wl[row * 2 + 1];
    r0 += hv[j] * Wr[row * 2 + 0];
    r1 += hv[j] * Wr[row * 2 + 1];
  }
#pragma unroll
  for (int off = 1; off < 64; off <<= 1) {
    l0 += __shfl_xor(l0, off);
    l1 += __shfl_xor(l1, off);
    r0 += __shfl_xor(r0, off);
    r1 += __shfl_xor(r1, off);
  }
  if (lane == 0) {
    xl2[node * 2 + 0] = l0; xl2[node * 2 + 1] = l1;
    xr2[node * 2 + 0] = r0; xr2[node * 2 + 1] = r1;
  }
}

// ---------------- layer 2 attention + log_softmax (thread per node) ----------------
__global__ __launch_bounds__(256) void gat2_out_kernel(const float* __restrict__ xl2,
                                                       const float* __restrict__ xr2,
                                                       const float* __restrict__ att2,
                                                       const float* __restrict__ b2,
                                                       const int* __restrict__ offsets,
                                                       const int* __restrict__ srcs,
                                                       float* __restrict__ out) {
  int node = blockIdx.x * blockDim.x + threadIdx.x;
  if (node >= NN) return;
  float a0 = att2[0], a1 = att2[1];
  float xr0 = xr2[node * 2 + 0], xr1 = xr2[node * 2 + 1];
  int beg = offsets[node], end = offsets[node + 1];
  float m_run = -1e30f, l_run = 0.f, o0 = 0.f, o1 = 0.f;
  for (int i = beg; i < end; ++i) {
    int s = srcs[i];
    float x0 = xl2[s * 2 + 0], x1 = xl2[s * 2 + 1];
    float e = lrelu(x0 + xr0) * a0 + lrelu(x1 + xr1) * a1;
    float mn = fmaxf(m_run, e);
    float sc = __expf(m_run - mn);
    float p = __expf(e - mn);
    l_run = l_run * sc + p;
    o0 = o0 * sc + p * x0;
    o1 = o1 * sc + p * x1;
    m_run = mn;
  }
  float inv = 1.f / l_run;
  float t0 = o0 * inv + b2[0];
  float t1 = o1 * inv + b2[1];
  float mx = fmaxf(t0, t1);
  float ls = mx + logf(__expf(t0 - mx) + __expf(t1 - mx));
  out[node * 2 + 0] = t0 - ls;
  out[node * 2 + 1] = t1 - ls;
}

extern "C" void kernel_launch(void* const* d_in, const int* in_sizes, int n_in,
                              void* d_out, int out_size, void* d_ws, size_t ws_size,
                              hipStream_t stream) {
  const float* x    = (const float*)d_in[0];
  const int*   ei   = (const int*)d_in[1];
  const float* Wl0  = (const float*)d_in[2];
  const float* Wr0  = (const float*)d_in[3];
  const float* att0 = (const float*)d_in[4];
  const float* b0   = (const float*)d_in[5];
  const float* g0   = (const float*)d_in[6];
  const float* be0  = (const float*)d_in[7];
  const float* m0   = (const float*)d_in[8];
  const float* v0   = (const float*)d_in[9];
  const float* Wl1  = (const float*)d_in[10];
  const float* Wr1  = (const float*)d_in[11];
  const float* att1 = (const float*)d_in[12];
  const float* b1   = (const float*)d_in[13];
  const float* g1   = (const float*)d_in[14];
  const float* be1  = (const float*)d_in[15];
  const float* m1   = (const float*)d_in[16];
  const float* v1   = (const float*)d_in[17];
  const float* Wl2  = (const float*)d_in[18];
  const float* Wr2  = (const float*)d_in[19];
  const float* att2 = (const float*)d_in[20];
  const float* b2   = (const float*)d_in[21];

  // workspace layout (≈64.3 MB)
  float* xlr = (float*)d_ws;                               // NN*512 fp32
  unsigned short* xb = (unsigned short*)(xlr + (size_t)NN * 512);  // MP*512 bf16 (A for layer0)
  unsigned short* hb = xb;                                 // MP*256 bf16 (alias: xb dead after GEMM0)
  unsigned short* Wf0 = xb + (size_t)MP * 512;             // 512*512 bf16
  unsigned short* Wf1 = Wf0 + 512 * 512;                   // 512*256 bf16
  float* xl2 = (float*)(Wf1 + 512 * 256);                  // 2*NN
  float* xr2 = xl2 + 2 * NN;                               // 2*NN
  int* offsets = (int*)(xr2 + 2 * NN);                     // NN+1
  int* cursor  = offsets + (NN + 1);                       // NN
  int* srcs    = cursor + NN;                              // ET

  // --- CSR build + input conversion ---
  hipMemsetAsync(cursor, 0, NN * sizeof(int), stream);
  hist_kernel<<<(ET + 255) / 256, 256, 0, stream>>>(ei, cursor);
  convert_x_kernel<<<(NN * 512 / 4 + 255) / 256, 256, 0, stream>>>(x, xb);
  convert_w_kernel<<<(512 * 512 + 255) / 256, 256, 0, stream>>>(Wl0, Wr0, Wf0, 512);
  convert_w_kernel<<<(512 * 256 + 255) / 256, 256, 0, stream>>>(Wl1, Wr1, Wf1, 256);
  scan_kernel<<<1, 1024, 0, stream>>>(cursor, offsets);
  scatter_kernel<<<(ET + 255) / 256, 256, 0, stream>>>(ei, cursor, srcs);

  dim3 gemm_grid(4, MP / 128);  // N=512 / 128, M=20096 / 128
  // --- layer 0 ---
  gemm_mfma<<<gemm_grid, 256, 0, stream>>>(xb, Wf0, xlr, NN, 512);
  gat_layer<<<NN / 4, 256, 0, stream>>>(xlr, att0, b0, g0, be0, m0, v0, offsets, srcs, hb);
  // --- layer 1 ---
  gemm_mfma<<<gemm_grid, 256, 0, stream>>>(hb, Wf1, xlr, NN, 256);
  gat_layer<<<NN / 4, 256, 0, stream>>>(xlr, att1, b1, g1, be1, m1, v1, offsets, srcs, hb);
  // --- layer 2 ---
  lin2_kernel<<<NN / 4, 256, 0, stream>>>(hb, Wl2, Wr2, xl2, xr2);
  gat2_out_kernel<<<(NN + 255) / 256, 256, 0, stream>>>(xl2, xr2, att2, b2, offsets, srcs, (float*)d_out);
}

// Round 3
// 347.144 us; speedup vs baseline: 1.7699x; 1.1093x over previous
//
#include <hip/hip_runtime.h>
#include <math.h>

#define NN 20000
#define MP 20096          // NN padded to multiple of 128 for MFMA GEMM A-reads
#define EE 320000
#define ET (EE + NN)
#define HC 256
#define EPS_BN 1e-5f

typedef __bf16 bf16x8 __attribute__((ext_vector_type(8)));
typedef float f32x4 __attribute__((ext_vector_type(4)));

__device__ __forceinline__ float4 ld4(const float* p) { return *reinterpret_cast<const float4*>(p); }
__device__ __forceinline__ float lrelu(float x) { return fmaxf(x, 0.f) + 0.2f * fminf(x, 0.f); }

// fp32 -> bf16 (RNE), raw ushort storage
__device__ __forceinline__ unsigned short f2b(float f) {
  unsigned int u = __float_as_uint(f);
  u = (u + 0x7fffu + ((u >> 16) & 1u)) >> 16;
  return (unsigned short)u;
}
__device__ __forceinline__ float b2f(unsigned short u) {
  return __uint_as_float(((unsigned int)u) << 16);
}

// async global->LDS, 16B per lane; LDS dest = wave-uniform base + lane*16
__device__ __forceinline__ void gld_lds16(const void* g, void* l) {
  __builtin_amdgcn_global_load_lds(
      (const __attribute__((address_space(1))) unsigned int*)g,
      (__attribute__((address_space(3))) unsigned int*)(unsigned int)(unsigned long long)l,
      16, 0, 0);
}

// ---------------- conversions ----------------
__global__ __launch_bounds__(256) void convert_x_kernel(const float* __restrict__ x,
                                                        unsigned short* __restrict__ xb) {
  int i = (blockIdx.x * 256 + threadIdx.x) * 4;
  if (i >= NN * 512) return;
  float4 v = ld4(&x[i]);
  ushort4 o;
  o.x = f2b(v.x); o.y = f2b(v.y); o.z = f2b(v.z); o.w = f2b(v.w);
  *reinterpret_cast<ushort4*>(&xb[i]) = o;
}

// Wf[n][k] = (n<256 ? Wl[k][n] : Wr[k][n-256])  (B^T layout, bf16)
__global__ __launch_bounds__(256) void convert_w_kernel(const float* __restrict__ Wl,
                                                        const float* __restrict__ Wr,
                                                        unsigned short* __restrict__ Wf,
                                                        int K) {
  int idx = blockIdx.x * 256 + threadIdx.x;
  if (idx >= 512 * K) return;
  int n = idx / K, k = idx - n * K;
  float v = (n < 256) ? Wl[(size_t)k * 256 + n] : Wr[(size_t)k * 256 + (n - 256)];
  Wf[idx] = f2b(v);
}

// ---------------- bf16 MFMA GEMM ----------------
// C = A[Mp,K] @ Bt[512,K]^T. Cols 0..255 (xl) -> bf16 xlb[M,256]; cols 256..511 (xr) -> fp32 xrf[M,256].
__global__ __launch_bounds__(256) void gemm_mfma(const unsigned short* __restrict__ A,
                                                 const unsigned short* __restrict__ Bt,
                                                 unsigned short* __restrict__ xlb,
                                                 float* __restrict__ xrf,
                                                 int M, int K) {
  __shared__ unsigned short As[128 * 32];  // [r][k], 8 KB
  __shared__ unsigned short Bs[128 * 32];  // [n][k], 8 KB
  const int wave = threadIdx.x >> 6;
  const int lane = threadIdx.x & 63;
  const int am = lane & 15;
  const int aq = lane >> 4;
  const int wr = (wave >> 1) * 64;
  const int wc = (wave & 1) * 64;
  const int row0 = blockIdx.y * 128;
  const int col0 = blockIdx.x * 128;

  f32x4 acc[4][4] = {};

  for (int kk = 0; kk < K; kk += 32) {
    __syncthreads();
#pragma unroll
    for (int c = 0; c < 2; ++c) {
      int seg = wave * 128 + c * 64 + lane;
      int r = seg >> 2, ks = (seg & 3) * 8;
      gld_lds16(A + (size_t)(row0 + r) * K + kk + ks, &As[(wave * 128 + c * 64) * 8]);
      gld_lds16(Bt + (size_t)(col0 + r) * K + kk + ks, &Bs[(wave * 128 + c * 64) * 8]);
    }
    __syncthreads();

    bf16x8 af[4], bfr[4];
#pragma unroll
    for (int i = 0; i < 4; ++i)
      af[i] = *reinterpret_cast<const bf16x8*>(&As[(wr + i * 16 + am) * 32 + aq * 8]);
#pragma unroll
    for (int j = 0; j < 4; ++j)
      bfr[j] = *reinterpret_cast<const bf16x8*>(&Bs[(wc + j * 16 + am) * 32 + aq * 8]);
#pragma unroll
    for (int i = 0; i < 4; ++i)
#pragma unroll
      for (int j = 0; j < 4; ++j)
        acc[i][j] = __builtin_amdgcn_mfma_f32_16x16x32_bf16(af[i], bfr[j], acc[i][j], 0, 0, 0);
  }

  // epilogue: D col = lane&15, row = (lane>>4)*4 + reg
#pragma unroll
  for (int i = 0; i < 4; ++i) {
#pragma unroll
    for (int j = 0; j < 4; ++j) {
      int gcol = col0 + wc + j * 16 + am;
#pragma unroll
      for (int rr = 0; rr < 4; ++rr) {
        int grow = row0 + wr + i * 16 + aq * 4 + rr;
        if (grow < M) {
          float v = acc[i][j][rr];
          if (gcol < 256) xlb[(size_t)grow * 256 + gcol] = f2b(v);
          else            xrf[(size_t)grow * 256 + (gcol - 256)] = v;
        }
      }
    }
  }
}

// ---------------- CSR build (counting sort by dst) ----------------
__global__ __launch_bounds__(256) void hist_kernel(const int* __restrict__ ei,
                                                   int* __restrict__ counts) {
  int e = blockIdx.x * blockDim.x + threadIdx.x;
  if (e >= ET) return;
  int d = (e < EE) ? ei[EE + e] : (e - EE);
  atomicAdd(&counts[d], 1);
}

// single-block scan: 1024 threads x 20 ints each, shfl-based, 2 barriers
__global__ __launch_bounds__(1024) void scan_kernel(int* __restrict__ cursor,
                                                    int* __restrict__ offsets) {
  __shared__ int wsum[16];
  const int tid = threadIdx.x;
  const int lane = tid & 63, wv = tid >> 6;
  const int base = tid * 20;
  int vals[20];
  int s = 0;
  if (tid < 1000) {
#pragma unroll
    for (int j = 0; j < 20; ++j) { vals[j] = cursor[base + j]; s += vals[j]; }
  }
  int ssum = s;  // inclusive wave scan
#pragma unroll
  for (int off = 1; off < 64; off <<= 1) {
    int t = __shfl_up(ssum, off);
    if (lane >= off) ssum += t;
  }
  if (lane == 63) wsum[wv] = ssum;
  __syncthreads();
  if (wv == 0) {
    int w = (lane < 16) ? wsum[lane] : 0;
#pragma unroll
    for (int off = 1; off < 16; off <<= 1) {
      int t = __shfl_up(w, off);
      if (lane >= off) w += t;
    }
    if (lane < 16) wsum[lane] = w;
  }
  __syncthreads();
  int excl = ssum - s + (wv > 0 ? wsum[wv - 1] : 0);
  if (tid < 1000) {
    int run = excl;
#pragma unroll
    for (int j = 0; j < 20; ++j) { offsets[base + j] = run; cursor[base + j] = run; run += vals[j]; }
  }
  if (tid == 1023) offsets[NN] = wsum[15];
}

__global__ __launch_bounds__(256) void scatter_kernel(const int* __restrict__ ei,
                                                      int* __restrict__ cursor,
                                                      int* __restrict__ srcs) {
  int e = blockIdx.x * blockDim.x + threadIdx.x;
  if (e >= ET) return;
  int s, d;
  if (e < EE) { s = ei[e]; d = ei[EE + e]; } else { s = d = e - EE; }
  int pos = atomicAdd(&cursor[d], 1);
  srcs[pos] = s;
}

// ---------------- GATv2 layer: wave/node, bf16 xl gather, online softmax, BN+ELU, bf16 out ----------------
__global__ __launch_bounds__(256) void gat_layer(const unsigned short* __restrict__ xlb,
                                                 const float* __restrict__ xrf,
                                                 const float* __restrict__ att,
                                                 const float* __restrict__ bias,
                                                 const float* __restrict__ gam,
                                                 const float* __restrict__ bet,
                                                 const float* __restrict__ mean,
                                                 const float* __restrict__ var,
                                                 const int* __restrict__ offsets,
                                                 const int* __restrict__ srcs,
                                                 unsigned short* __restrict__ hb) {
  const int wave = threadIdx.x >> 6;
  const int lane = threadIdx.x & 63;
  const int node = blockIdx.x * 4 + wave;
  if (node >= NN) return;

  const float4 xr4 = ld4(&xrf[(size_t)node * HC + lane * 4]);
  const float4 a4 = ld4(&att[lane * 4]);
  const int beg = offsets[node];
  const int end = offsets[node + 1];

  float m_run = -1e30f, l_run = 0.f;
  float4 O = make_float4(0.f, 0.f, 0.f, 0.f);

  for (int i = beg; i < end; ++i) {
    int s = srcs[i];
    ushort4 u = *reinterpret_cast<const ushort4*>(&xlb[(size_t)s * HC + lane * 4]);
    float x0 = b2f(u.x), x1 = b2f(u.y), x2 = b2f(u.z), x3 = b2f(u.w);
    float loc = lrelu(x0 + xr4.x) * a4.x + lrelu(x1 + xr4.y) * a4.y +
                lrelu(x2 + xr4.z) * a4.z + lrelu(x3 + xr4.w) * a4.w;
    loc += __shfl_xor(loc, 1);
    loc += __shfl_xor(loc, 2);
    loc += __shfl_xor(loc, 4);
    loc += __shfl_xor(loc, 8);   // all 16 lanes of this head hold e_h
    float mn = fmaxf(m_run, loc);
    float sc = __expf(m_run - mn);
    float p = __expf(loc - mn);
    l_run = l_run * sc + p;
    O.x = O.x * sc + p * x0;
    O.y = O.y * sc + p * x1;
    O.z = O.z * sc + p * x2;
    O.w = O.w * sc + p * x3;
    m_run = mn;
  }
  float inv = 1.f / l_run;

  float4 b4 = ld4(&bias[lane * 4]);
  float4 g4 = ld4(&gam[lane * 4]);
  float4 e4 = ld4(&bet[lane * 4]);
  float4 m4 = ld4(&mean[lane * 4]);
  float4 v4 = ld4(&var[lane * 4]);
  float y0 = O.x * inv + b4.x, y1 = O.y * inv + b4.y;
  float y2 = O.z * inv + b4.z, y3 = O.w * inv + b4.w;
  float z0 = (y0 - m4.x) * (g4.x * rsqrtf(v4.x + EPS_BN)) + e4.x;
  float z1 = (y1 - m4.y) * (g4.y * rsqrtf(v4.y + EPS_BN)) + e4.y;
  float z2 = (y2 - m4.z) * (g4.z * rsqrtf(v4.z + EPS_BN)) + e4.z;
  float z3 = (y3 - m4.w) * (g4.w * rsqrtf(v4.w + EPS_BN)) + e4.w;
  ushort4 r;
  r.x = f2b(z0 > 0.f ? z0 : expm1f(z0));
  r.y = f2b(z1 > 0.f ? z1 : expm1f(z1));
  r.z = f2b(z2 > 0.f ? z2 : expm1f(z2));
  r.w = f2b(z3 > 0.f ? z3 : expm1f(z3));
  *reinterpret_cast<ushort4*>(&hb[(size_t)node * HC + lane * 4]) = r;
}

// ---------------- layer 2: 256 -> 2 projections (wave per node, bf16 input) ----------------
__global__ __launch_bounds__(256) void lin2_kernel(const unsigned short* __restrict__ hb,
                                                   const float* __restrict__ Wl,
                                                   const float* __restrict__ Wr,
                                                   float* __restrict__ xl2,
                                                   float* __restrict__ xr2) {
  const int wave = threadIdx.x >> 6;
  const int lane = threadIdx.x & 63;
  const int node = blockIdx.x * 4 + wave;
  if (node >= NN) return;
  ushort4 h4 = *reinterpret_cast<const ushort4*>(&hb[(size_t)node * HC + lane * 4]);
  float hv[4] = {b2f(h4.x), b2f(h4.y), b2f(h4.z), b2f(h4.w)};
  float l0 = 0.f, l1 = 0.f, r0 = 0.f, r1 = 0.f;
#pragma unroll
  for (int j = 0; j < 4; ++j) {
    int row = lane * 4 + j;
    l0 += hv[j] * Wl[row * 2 + 0];
    l1 += hv[j] * Wl[row * 2 + 1];
    r0 += hv[j] * Wr[row * 2 + 0];
    r1 += hv[j] * Wr[row * 2 + 1];
  }
#pragma unroll
  for (int off = 1; off < 64; off <<= 1) {
    l0 += __shfl_xor(l0, off);
    l1 += __shfl_xor(l1, off);
    r0 += __shfl_xor(r0, off);
    r1 += __shfl_xor(r1, off);
  }
  if (lane == 0) {
    xl2[node * 2 + 0] = l0; xl2[node * 2 + 1] = l1;
    xr2[node * 2 + 0] = r0; xr2[node * 2 + 1] = r1;
  }
}

// ---------------- layer 2 attention + log_softmax (wave per node, lane per edge) ----------------
__global__ __launch_bounds__(256) void gat2_out_kernel(const float* __restrict__ xl2,
                                                       const float* __restrict__ xr2,
                                                       const float* __restrict__ att2,
                                                       const float* __restrict__ b2,
                                                       const int* __restrict__ offsets,
                                                       const int* __restrict__ srcs,
                                                       float* __restrict__ out) {
  const int wave = threadIdx.x >> 6;
  const int lane = threadIdx.x & 63;
  const int node = blockIdx.x * 4 + wave;
  if (node >= NN) return;
  const float a0 = att2[0], a1 = att2[1];
  const float xr0 = xr2[node * 2 + 0], xr1 = xr2[node * 2 + 1];
  const int beg = offsets[node], end = offsets[node + 1];

  float m = -1e30f, l = 0.f, o0 = 0.f, o1 = 0.f;
  for (int i = beg + lane; i < end; i += 64) {
    int s = srcs[i];
    float x0 = xl2[s * 2 + 0], x1 = xl2[s * 2 + 1];
    float e = lrelu(x0 + xr0) * a0 + lrelu(x1 + xr1) * a1;
    float mn = fmaxf(m, e);
    float sc = __expf(m - mn);
    float p = __expf(e - mn);
    l = l * sc + p;
    o0 = o0 * sc + p * x0;
    o1 = o1 * sc + p * x1;
    m = mn;
  }
  // merge online-softmax state across 64 lanes
#pragma unroll
  for (int off = 1; off < 64; off <<= 1) {
    float m2 = __shfl_xor(m, off);
    float l2 = __shfl_xor(l, off);
    float p0 = __shfl_xor(o0, off);
    float p1 = __shfl_xor(o1, off);
    float mn = fmaxf(m, m2);
    float sa = __expf(m - mn);
    float sb = __expf(m2 - mn);
    l = l * sa + l2 * sb;
    o0 = o0 * sa + p0 * sb;
    o1 = o1 * sa + p1 * sb;
    m = mn;
  }
  if (lane == 0) {
    float inv = 1.f / l;
    float t0 = o0 * inv + b2[0];
    float t1 = o1 * inv + b2[1];
    float mx = fmaxf(t0, t1);
    float ls = mx + logf(__expf(t0 - mx) + __expf(t1 - mx));
    out[node * 2 + 0] = t0 - ls;
    out[node * 2 + 1] = t1 - ls;
  }
}

extern "C" void kernel_launch(void* const* d_in, const int* in_sizes, int n_in,
                              void* d_out, int out_size, void* d_ws, size_t ws_size,
                              hipStream_t stream) {
  const float* x    = (const float*)d_in[0];
  const int*   ei   = (const int*)d_in[1];
  const float* Wl0  = (const float*)d_in[2];
  const float* Wr0  = (const float*)d_in[3];
  const float* att0 = (const float*)d_in[4];
  const float* b0   = (const float*)d_in[5];
  const float* g0   = (const float*)d_in[6];
  const float* be0  = (const float*)d_in[7];
  const float* m0   = (const float*)d_in[8];
  const float* v0   = (const float*)d_in[9];
  const float* Wl1  = (const float*)d_in[10];
  const float* Wr1  = (const float*)d_in[11];
  const float* att1 = (const float*)d_in[12];
  const float* b1   = (const float*)d_in[13];
  const float* g1   = (const float*)d_in[14];
  const float* be1  = (const float*)d_in[15];
  const float* m1   = (const float*)d_in[16];
  const float* v1   = (const float*)d_in[17];
  const float* Wl2  = (const float*)d_in[18];
  const float* Wr2  = (const float*)d_in[19];
  const float* att2 = (const float*)d_in[20];
  const float* b2   = (const float*)d_in[21];

  // workspace layout (~64.2 MB)
  float* xrf = (float*)d_ws;                                   // NN*256 fp32
  unsigned short* xlb = (unsigned short*)(xrf + (size_t)NN * 256);  // NN*256 bf16
  unsigned short* hb  = xlb + (size_t)NN * 256;                // MP*256 bf16
  unsigned short* xb  = hb + (size_t)MP * 256;                 // MP*512 bf16
  unsigned short* Wf0 = xb + (size_t)MP * 512;                 // 512*512 bf16
  unsigned short* Wf1 = Wf0 + 512 * 512;                       // 512*256 bf16
  float* xl2 = (float*)(Wf1 + 512 * 256);                      // 2*NN
  float* xr2 = xl2 + 2 * NN;                                   // 2*NN
  int* offsets = (int*)(xr2 + 2 * NN);                         // NN+1
  int* cursor  = offsets + (NN + 1);                           // NN
  int* srcs    = cursor + NN;                                  // ET

  // --- CSR build + input conversion ---
  hipMemsetAsync(cursor, 0, NN * sizeof(int), stream);
  hist_kernel<<<(ET + 255) / 256, 256, 0, stream>>>(ei, cursor);
  convert_x_kernel<<<(NN * 512 / 4 + 255) / 256, 256, 0, stream>>>(x, xb);
  convert_w_kernel<<<(512 * 512 + 255) / 256, 256, 0, stream>>>(Wl0, Wr0, Wf0, 512);
  convert_w_kernel<<<(512 * 256 + 255) / 256, 256, 0, stream>>>(Wl1, Wr1, Wf1, 256);
  scan_kernel<<<1, 1024, 0, stream>>>(cursor, offsets);
  scatter_kernel<<<(ET + 255) / 256, 256, 0, stream>>>(ei, cursor, srcs);

  dim3 gemm_grid(4, MP / 128);
  // --- layer 0 ---
  gemm_mfma<<<gemm_grid, 256, 0, stream>>>(xb, Wf0, xlb, xrf, NN, 512);
  gat_layer<<<NN / 4, 256, 0, stream>>>(xlb, xrf, att0, b0, g0, be0, m0, v0, offsets, srcs, hb);
  // --- layer 1 ---
  gemm_mfma<<<gemm_grid, 256, 0, stream>>>(hb, Wf1, xlb, xrf, NN, 256);
  gat_layer<<<NN / 4, 256, 0, stream>>>(xlb, xrf, att1, b1, g1, be1, m1, v1, offsets, srcs, hb);
  // --- layer 2 ---
  lin2_kernel<<<NN / 4, 256, 0, stream>>>(hb, Wl2, Wr2, xl2, xr2);
  gat2_out_kernel<<<NN / 4, 256, 0, stream>>>(xl2, xr2, att2, b2, offsets, srcs, (float*)d_out);
}

// Round 4
// 301.571 us; speedup vs baseline: 2.0374x; 1.1511x over previous
//
#include <hip/hip_runtime.h>
#include <math.h>

#define NN 20000
#define MP 20096          // NN padded to multiple of 128 for MFMA GEMM A-reads
#define EE 320000
#define ET (EE + NN)
#define HC 256
#define EPS_BN 1e-5f

typedef __bf16 bf16x8 __attribute__((ext_vector_type(8)));
typedef float f32x4 __attribute__((ext_vector_type(4)));

__device__ __forceinline__ float4 ld4(const float* p) { return *reinterpret_cast<const float4*>(p); }
__device__ __forceinline__ float lrelu(float x) { return fmaxf(x, 0.f) + 0.2f * fminf(x, 0.f); }

// fp32 -> bf16 (RNE), raw ushort storage
__device__ __forceinline__ unsigned short f2b(float f) {
  unsigned int u = __float_as_uint(f);
  u = (u + 0x7fffu + ((u >> 16) & 1u)) >> 16;
  return (unsigned short)u;
}
__device__ __forceinline__ float b2f(unsigned short u) {
  return __uint_as_float(((unsigned int)u) << 16);
}

// async global->LDS, 16B per lane; LDS dest = wave-uniform base + lane*16
__device__ __forceinline__ void gld_lds16(const void* g, void* l) {
  __builtin_amdgcn_global_load_lds(
      (const __attribute__((address_space(1))) unsigned int*)g,
      (__attribute__((address_space(3))) unsigned int*)(unsigned int)(unsigned long long)l,
      16, 0, 0);
}

// ---------------- conversions ----------------
__global__ __launch_bounds__(256) void convert_x_kernel(const float* __restrict__ x,
                                                        unsigned short* __restrict__ xb) {
  int i = (blockIdx.x * 256 + threadIdx.x) * 4;
  if (i >= NN * 512) return;
  float4 v = ld4(&x[i]);
  ushort4 o;
  o.x = f2b(v.x); o.y = f2b(v.y); o.z = f2b(v.z); o.w = f2b(v.w);
  *reinterpret_cast<ushort4*>(&xb[i]) = o;
}

// Wf[n][k] = (n<256 ? Wl[k][n] : Wr[k][n-256])  (B^T layout, bf16)
__global__ __launch_bounds__(256) void convert_w_kernel(const float* __restrict__ Wl,
                                                        const float* __restrict__ Wr,
                                                        unsigned short* __restrict__ Wf,
                                                        int K) {
  int idx = blockIdx.x * 256 + threadIdx.x;
  if (idx >= 512 * K) return;
  int n = idx / K, k = idx - n * K;
  float v = (n < 256) ? Wl[(size_t)k * 256 + n] : Wr[(size_t)k * 256 + (n - 256)];
  Wf[idx] = f2b(v);
}

// ---------------- bf16 MFMA GEMM ----------------
// C = A[Mp,K] @ Bt[512,K]^T. Cols 0..255 (xl) -> bf16 xlb[M,256]; cols 256..511 (xr) -> fp32 xrf[M,256].
__global__ __launch_bounds__(256) void gemm_mfma(const unsigned short* __restrict__ A,
                                                 const unsigned short* __restrict__ Bt,
                                                 unsigned short* __restrict__ xlb,
                                                 float* __restrict__ xrf,
                                                 int M, int K) {
  __shared__ unsigned short As[128 * 32];  // [r][k], 8 KB
  __shared__ unsigned short Bs[128 * 32];  // [n][k], 8 KB
  const int wave = threadIdx.x >> 6;
  const int lane = threadIdx.x & 63;
  const int am = lane & 15;
  const int aq = lane >> 4;
  const int wr = (wave >> 1) * 64;
  const int wc = (wave & 1) * 64;
  const int row0 = blockIdx.y * 128;
  const int col0 = blockIdx.x * 128;

  f32x4 acc[4][4] = {};

  for (int kk = 0; kk < K; kk += 32) {
    __syncthreads();
#pragma unroll
    for (int c = 0; c < 2; ++c) {
      int seg = wave * 128 + c * 64 + lane;
      int r = seg >> 2, ks = (seg & 3) * 8;
      gld_lds16(A + (size_t)(row0 + r) * K + kk + ks, &As[(wave * 128 + c * 64) * 8]);
      gld_lds16(Bt + (size_t)(col0 + r) * K + kk + ks, &Bs[(wave * 128 + c * 64) * 8]);
    }
    __syncthreads();

    bf16x8 af[4], bfr[4];
#pragma unroll
    for (int i = 0; i < 4; ++i)
      af[i] = *reinterpret_cast<const bf16x8*>(&As[(wr + i * 16 + am) * 32 + aq * 8]);
#pragma unroll
    for (int j = 0; j < 4; ++j)
      bfr[j] = *reinterpret_cast<const bf16x8*>(&Bs[(wc + j * 16 + am) * 32 + aq * 8]);
#pragma unroll
    for (int i = 0; i < 4; ++i)
#pragma unroll
      for (int j = 0; j < 4; ++j)
        acc[i][j] = __builtin_amdgcn_mfma_f32_16x16x32_bf16(af[i], bfr[j], acc[i][j], 0, 0, 0);
  }

  // epilogue: D col = lane&15, row = (lane>>4)*4 + reg
#pragma unroll
  for (int i = 0; i < 4; ++i) {
#pragma unroll
    for (int j = 0; j < 4; ++j) {
      int gcol = col0 + wc + j * 16 + am;
#pragma unroll
      for (int rr = 0; rr < 4; ++rr) {
        int grow = row0 + wr + i * 16 + aq * 4 + rr;
        if (grow < M) {
          float v = acc[i][j][rr];
          if (gcol < 256) xlb[(size_t)grow * 256 + gcol] = f2b(v);
          else            xrf[(size_t)grow * 256 + (gcol - 256)] = v;
        }
      }
    }
  }
}

// ---------------- CSR build (counting sort by dst) ----------------
__global__ __launch_bounds__(256) void hist_kernel(const int* __restrict__ ei,
                                                   int* __restrict__ counts) {
  int e = blockIdx.x * blockDim.x + threadIdx.x;
  if (e >= ET) return;
  int d = (e < EE) ? ei[EE + e] : (e - EE);
  atomicAdd(&counts[d], 1);
}

// single-block scan: 1024 threads x 20 ints each, shfl-based, 2 barriers
__global__ __launch_bounds__(1024) void scan_kernel(int* __restrict__ cursor,
                                                    int* __restrict__ offsets) {
  __shared__ int wsum[16];
  const int tid = threadIdx.x;
  const int lane = tid & 63, wv = tid >> 6;
  const int base = tid * 20;
  int vals[20];
  int s = 0;
  if (tid < 1000) {
#pragma unroll
    for (int j = 0; j < 20; ++j) { vals[j] = cursor[base + j]; s += vals[j]; }
  }
  int ssum = s;  // inclusive wave scan
#pragma unroll
  for (int off = 1; off < 64; off <<= 1) {
    int t = __shfl_up(ssum, off);
    if (lane >= off) ssum += t;
  }
  if (lane == 63) wsum[wv] = ssum;
  __syncthreads();
  if (wv == 0) {
    int w = (lane < 16) ? wsum[lane] : 0;
#pragma unroll
    for (int off = 1; off < 16; off <<= 1) {
      int t = __shfl_up(w, off);
      if (lane >= off) w += t;
    }
    if (lane < 16) wsum[lane] = w;
  }
  __syncthreads();
  int excl = ssum - s + (wv > 0 ? wsum[wv - 1] : 0);
  if (tid < 1000) {
    int run = excl;
#pragma unroll
    for (int j = 0; j < 20; ++j) { offsets[base + j] = run; cursor[base + j] = run; run += vals[j]; }
  }
  if (tid == 1023) offsets[NN] = wsum[15];
}

__global__ __launch_bounds__(256) void scatter_kernel(const int* __restrict__ ei,
                                                      int* __restrict__ cursor,
                                                      int* __restrict__ srcs) {
  int e = blockIdx.x * blockDim.x + threadIdx.x;
  if (e >= ET) return;
  int s, d;
  if (e < EE) { s = ei[e]; d = ei[EE + e]; } else { s = d = e - EE; }
  int pos = atomicAdd(&cursor[d], 1);
  srcs[pos] = s;
}

// ---------------- GATv2 layer: wave/node, NO-max softmax (|e|<~3 by construction), ----------------
// 4-edge unroll, dual accumulator banks, BN+ELU epilogue, bf16 out
__global__ __launch_bounds__(256) void gat_layer(const unsigned short* __restrict__ xlb,
                                                 const float* __restrict__ xrf,
                                                 const float* __restrict__ att,
                                                 const float* __restrict__ bias,
                                                 const float* __restrict__ gam,
                                                 const float* __restrict__ bet,
                                                 const float* __restrict__ mean,
                                                 const float* __restrict__ var,
                                                 const int* __restrict__ offsets,
                                                 const int* __restrict__ srcs,
                                                 unsigned short* __restrict__ hb) {
  const int wave = threadIdx.x >> 6;
  const int lane = threadIdx.x & 63;
  const int node = blockIdx.x * 4 + wave;
  if (node >= NN) return;

  const float4 xr4 = ld4(&xrf[(size_t)node * HC + lane * 4]);
  const float4 a4 = ld4(&att[lane * 4]);
  const int beg = offsets[node];
  const int end = offsets[node + 1];

  float lA = 0.f, lB = 0.f;
  float4 OA = make_float4(0.f, 0.f, 0.f, 0.f);
  float4 OB = make_float4(0.f, 0.f, 0.f, 0.f);

  int i = beg;
  for (; i + 3 < end; i += 4) {
    int s0 = srcs[i], s1 = srcs[i + 1], s2 = srcs[i + 2], s3 = srcs[i + 3];
    ushort4 u0 = *reinterpret_cast<const ushort4*>(&xlb[(size_t)s0 * HC + lane * 4]);
    ushort4 u1 = *reinterpret_cast<const ushort4*>(&xlb[(size_t)s1 * HC + lane * 4]);
    ushort4 u2 = *reinterpret_cast<const ushort4*>(&xlb[(size_t)s2 * HC + lane * 4]);
    ushort4 u3 = *reinterpret_cast<const ushort4*>(&xlb[(size_t)s3 * HC + lane * 4]);
    float4 x0 = make_float4(b2f(u0.x), b2f(u0.y), b2f(u0.z), b2f(u0.w));
    float4 x1 = make_float4(b2f(u1.x), b2f(u1.y), b2f(u1.z), b2f(u1.w));
    float4 x2 = make_float4(b2f(u2.x), b2f(u2.y), b2f(u2.z), b2f(u2.w));
    float4 x3 = make_float4(b2f(u3.x), b2f(u3.y), b2f(u3.z), b2f(u3.w));
    float e0 = lrelu(x0.x + xr4.x) * a4.x + lrelu(x0.y + xr4.y) * a4.y +
               lrelu(x0.z + xr4.z) * a4.z + lrelu(x0.w + xr4.w) * a4.w;
    float e1 = lrelu(x1.x + xr4.x) * a4.x + lrelu(x1.y + xr4.y) * a4.y +
               lrelu(x1.z + xr4.z) * a4.z + lrelu(x1.w + xr4.w) * a4.w;
    float e2 = lrelu(x2.x + xr4.x) * a4.x + lrelu(x2.y + xr4.y) * a4.y +
               lrelu(x2.z + xr4.z) * a4.z + lrelu(x2.w + xr4.w) * a4.w;
    float e3 = lrelu(x3.x + xr4.x) * a4.x + lrelu(x3.y + xr4.y) * a4.y +
               lrelu(x3.z + xr4.z) * a4.z + lrelu(x3.w + xr4.w) * a4.w;
#pragma unroll
    for (int off = 1; off < 16; off <<= 1) {
      e0 += __shfl_xor(e0, off);
      e1 += __shfl_xor(e1, off);
      e2 += __shfl_xor(e2, off);
      e3 += __shfl_xor(e3, off);
    }
    float p0 = __expf(e0), p1 = __expf(e1), p2 = __expf(e2), p3 = __expf(e3);
    lA += p0; lB += p1; lA += p2; lB += p3;
    OA.x += p0 * x0.x; OA.y += p0 * x0.y; OA.z += p0 * x0.z; OA.w += p0 * x0.w;
    OB.x += p1 * x1.x; OB.y += p1 * x1.y; OB.z += p1 * x1.z; OB.w += p1 * x1.w;
    OA.x += p2 * x2.x; OA.y += p2 * x2.y; OA.z += p2 * x2.z; OA.w += p2 * x2.w;
    OB.x += p3 * x3.x; OB.y += p3 * x3.y; OB.z += p3 * x3.z; OB.w += p3 * x3.w;
  }
  for (; i < end; ++i) {
    int s = srcs[i];
    ushort4 u = *reinterpret_cast<const ushort4*>(&xlb[(size_t)s * HC + lane * 4]);
    float4 x0 = make_float4(b2f(u.x), b2f(u.y), b2f(u.z), b2f(u.w));
    float e = lrelu(x0.x + xr4.x) * a4.x + lrelu(x0.y + xr4.y) * a4.y +
              lrelu(x0.z + xr4.z) * a4.z + lrelu(x0.w + xr4.w) * a4.w;
#pragma unroll
    for (int off = 1; off < 16; off <<= 1) e += __shfl_xor(e, off);
    float p = __expf(e);
    lA += p;
    OA.x += p * x0.x; OA.y += p * x0.y; OA.z += p * x0.z; OA.w += p * x0.w;
  }
  float inv = 1.f / (lA + lB);
  float4 O = make_float4(OA.x + OB.x, OA.y + OB.y, OA.z + OB.z, OA.w + OB.w);

  float4 b4 = ld4(&bias[lane * 4]);
  float4 g4 = ld4(&gam[lane * 4]);
  float4 e4 = ld4(&bet[lane * 4]);
  float4 m4 = ld4(&mean[lane * 4]);
  float4 v4 = ld4(&var[lane * 4]);
  float y0 = O.x * inv + b4.x, y1 = O.y * inv + b4.y;
  float y2 = O.z * inv + b4.z, y3 = O.w * inv + b4.w;
  float z0 = (y0 - m4.x) * (g4.x * rsqrtf(v4.x + EPS_BN)) + e4.x;
  float z1 = (y1 - m4.y) * (g4.y * rsqrtf(v4.y + EPS_BN)) + e4.y;
  float z2 = (y2 - m4.z) * (g4.z * rsqrtf(v4.z + EPS_BN)) + e4.z;
  float z3 = (y3 - m4.w) * (g4.w * rsqrtf(v4.w + EPS_BN)) + e4.w;
  ushort4 r;
  r.x = f2b(z0 > 0.f ? z0 : expm1f(z0));
  r.y = f2b(z1 > 0.f ? z1 : expm1f(z1));
  r.z = f2b(z2 > 0.f ? z2 : expm1f(z2));
  r.w = f2b(z3 > 0.f ? z3 : expm1f(z3));
  *reinterpret_cast<ushort4*>(&hb[(size_t)node * HC + lane * 4]) = r;
}

// ---------------- layer 2: 256 -> 2 projections (wave per node, bf16 input) ----------------
__global__ __launch_bounds__(256) void lin2_kernel(const unsigned short* __restrict__ hb,
                                                   const float* __restrict__ Wl,
                                                   const float* __restrict__ Wr,
                                                   float* __restrict__ xl2,
                                                   float* __restrict__ xr2) {
  const int wave = threadIdx.x >> 6;
  const int lane = threadIdx.x & 63;
  const int node = blockIdx.x * 4 + wave;
  if (node >= NN) return;
  ushort4 h4 = *reinterpret_cast<const ushort4*>(&hb[(size_t)node * HC + lane * 4]);
  float hv[4] = {b2f(h4.x), b2f(h4.y), b2f(h4.z), b2f(h4.w)};
  float l0 = 0.f, l1 = 0.f, r0 = 0.f, r1 = 0.f;
#pragma unroll
  for (int j = 0; j < 4; ++j) {
    int row = lane * 4 + j;
    l0 += hv[j] * Wl[row * 2 + 0];
    l1 += hv[j] * Wl[row * 2 + 1];
    r0 += hv[j] * Wr[row * 2 + 0];
    r1 += hv[j] * Wr[row * 2 + 1];
  }
#pragma unroll
  for (int off = 1; off < 64; off <<= 1) {
    l0 += __shfl_xor(l0, off);
    l1 += __shfl_xor(l1, off);
    r0 += __shfl_xor(r0, off);
    r1 += __shfl_xor(r1, off);
  }
  if (lane == 0) {
    xl2[node * 2 + 0] = l0; xl2[node * 2 + 1] = l1;
    xr2[node * 2 + 0] = r0; xr2[node * 2 + 1] = r1;
  }
}

// ---------------- layer 2 attention + log_softmax (wave per node, lane per edge, no-max) ----------------
__global__ __launch_bounds__(256) void gat2_out_kernel(const float* __restrict__ xl2,
                                                       const float* __restrict__ xr2,
                                                       const float* __restrict__ att2,
                                                       const float* __restrict__ b2,
                                                       const int* __restrict__ offsets,
                                                       const int* __restrict__ srcs,
                                                       float* __restrict__ out) {
  const int wave = threadIdx.x >> 6;
  const int lane = threadIdx.x & 63;
  const int node = blockIdx.x * 4 + wave;
  if (node >= NN) return;
  const float a0 = att2[0], a1 = att2[1];
  const float xr0 = xr2[node * 2 + 0], xr1 = xr2[node * 2 + 1];
  const int beg = offsets[node], end = offsets[node + 1];

  float l = 0.f, o0 = 0.f, o1 = 0.f;
  for (int i = beg + lane; i < end; i += 64) {
    int s = srcs[i];
    float x0 = xl2[s * 2 + 0], x1 = xl2[s * 2 + 1];
    float e = lrelu(x0 + xr0) * a0 + lrelu(x1 + xr1) * a1;
    float p = __expf(e);
    l += p;
    o0 += p * x0;
    o1 += p * x1;
  }
#pragma unroll
  for (int off = 1; off < 64; off <<= 1) {
    l += __shfl_xor(l, off);
    o0 += __shfl_xor(o0, off);
    o1 += __shfl_xor(o1, off);
  }
  if (lane == 0) {
    float inv = 1.f / l;
    float t0 = o0 * inv + b2[0];
    float t1 = o1 * inv + b2[1];
    float mx = fmaxf(t0, t1);
    float ls = mx + logf(__expf(t0 - mx) + __expf(t1 - mx));
    out[node * 2 + 0] = t0 - ls;
    out[node * 2 + 1] = t1 - ls;
  }
}

extern "C" void kernel_launch(void* const* d_in, const int* in_sizes, int n_in,
                              void* d_out, int out_size, void* d_ws, size_t ws_size,
                              hipStream_t stream) {
  const float* x    = (const float*)d_in[0];
  const int*   ei   = (const int*)d_in[1];
  const float* Wl0  = (const float*)d_in[2];
  const float* Wr0  = (const float*)d_in[3];
  const float* att0 = (const float*)d_in[4];
  const float* b0   = (const float*)d_in[5];
  const float* g0   = (const float*)d_in[6];
  const float* be0  = (const float*)d_in[7];
  const float* m0   = (const float*)d_in[8];
  const float* v0   = (const float*)d_in[9];
  const float* Wl1  = (const float*)d_in[10];
  const float* Wr1  = (const float*)d_in[11];
  const float* att1 = (const float*)d_in[12];
  const float* b1   = (const float*)d_in[13];
  const float* g1   = (const float*)d_in[14];
  const float* be1  = (const float*)d_in[15];
  const float* m1   = (const float*)d_in[16];
  const float* v1   = (const float*)d_in[17];
  const float* Wl2  = (const float*)d_in[18];
  const float* Wr2  = (const float*)d_in[19];
  const float* att2 = (const float*)d_in[20];
  const float* b2   = (const float*)d_in[21];

  // workspace layout (~64.2 MB)
  float* xrf = (float*)d_ws;                                   // NN*256 fp32
  unsigned short* xlb = (unsigned short*)(xrf + (size_t)NN * 256);  // NN*256 bf16
  unsigned short* hb  = xlb + (size_t)NN * 256;                // MP*256 bf16
  unsigned short* xb  = hb + (size_t)MP * 256;                 // MP*512 bf16
  unsigned short* Wf0 = xb + (size_t)MP * 512;                 // 512*512 bf16
  unsigned short* Wf1 = Wf0 + 512 * 512;                       // 512*256 bf16
  float* xl2 = (float*)(Wf1 + 512 * 256);                      // 2*NN
  float* xr2 = xl2 + 2 * NN;                                   // 2*NN
  int* offsets = (int*)(xr2 + 2 * NN);                         // NN+1
  int* cursor  = offsets + (NN + 1);                           // NN
  int* srcs    = cursor + NN;                                  // ET

  // --- CSR build + input conversion ---
  hipMemsetAsync(cursor, 0, NN * sizeof(int), stream);
  hist_kernel<<<(ET + 255) / 256, 256, 0, stream>>>(ei, cursor);
  convert_x_kernel<<<(NN * 512 / 4 + 255) / 256, 256, 0, stream>>>(x, xb);
  convert_w_kernel<<<(512 * 512 + 255) / 256, 256, 0, stream>>>(Wl0, Wr0, Wf0, 512);
  convert_w_kernel<<<(512 * 256 + 255) / 256, 256, 0, stream>>>(Wl1, Wr1, Wf1, 256);
  scan_kernel<<<1, 1024, 0, stream>>>(cursor, offsets);
  scatter_kernel<<<(ET + 255) / 256, 256, 0, stream>>>(ei, cursor, srcs);

  dim3 gemm_grid(4, MP / 128);
  // --- layer 0 ---
  gemm_mfma<<<gemm_grid, 256, 0, stream>>>(xb, Wf0, xlb, xrf, NN, 512);
  gat_layer<<<NN / 4, 256, 0, stream>>>(xlb, xrf, att0, b0, g0, be0, m0, v0, offsets, srcs, hb);
  // --- layer 1 ---
  gemm_mfma<<<gemm_grid, 256, 0, stream>>>(hb, Wf1, xlb, xrf, NN, 256);
  gat_layer<<<NN / 4, 256, 0, stream>>>(xlb, xrf, att1, b1, g1, be1, m1, v1, offsets, srcs, hb);
  // --- layer 2 ---
  lin2_kernel<<<NN / 4, 256, 0, stream>>>(hb, Wl2, Wr2, xl2, xr2);
  gat2_out_kernel<<<NN / 4, 256, 0, stream>>>(xl2, xr2, att2, b2, offsets, srcs, (float*)d_out);
}